// Round 3
// baseline (515.720 us; speedup 1.0000x reference)
//
#include <hip/hip_runtime.h>
#include <hip/hip_bf16.h>
#include <stdint.h>

typedef __attribute__((ext_vector_type(8))) short bf16x8;
typedef __attribute__((ext_vector_type(4))) float f32x4;

// explicit round-to-nearest-even f32 -> bf16
__device__ __forceinline__ uint32_t f2bfu(float x){
  union { float f; uint32_t u; } v; v.f = x;
  return (v.u + 0x7FFFu + ((v.u >> 16) & 1u)) >> 16;
}
__device__ __forceinline__ short f2bf(float x){ return (short)(uint16_t)f2bfu(x); }
// pack two f32 -> u32 of 2 bf16, RNE (lo = a, hi = b)
__device__ __forceinline__ uint32_t pk2(float a, float b){
  return (f2bfu(a) & 0xFFFFu) | (f2bfu(b) << 16);
}

__device__ __forceinline__ f32x4 mfma16(bf16x8 a, bf16x8 b, f32x4 c){
  return __builtin_amdgcn_mfma_f32_16x16x32_bf16(a, b, c, 0, 0, 0);
}

// ---------------- prep: fold E2 into N1 -----------------------------------
// Wfold[l] = We2[l] @ Wn1[l][64:128]  (64x64, fp32)
// bfold[l] = nb1[l] + eb2[l] @ Wn1[l][64:128]
__global__ void prep_fold(const float* __restrict__ ew2, const float* __restrict__ eb2,
                          const float* __restrict__ nw1, const float* __restrict__ nb1,
                          float* __restrict__ wfold, float* __restrict__ bfold)
{
  int l = blockIdx.x, t = threadIdx.x;
  const float* A  = ew2 + l*4096;            // We2 [64][64]
  const float* Bm = nw1 + l*8192 + 4096;     // Wn1b [64][64]
  for (int i = 0; i < 16; ++i){
    int idx = t + i*256;
    int r = idx >> 6, c = idx & 63;
    float s = 0.f;
    for (int m = 0; m < 64; ++m) s += A[r*64 + m] * Bm[m*64 + c];
    wfold[l*4096 + idx] = s;
  }
  if (t < 64){
    float s = nb1[l*64 + t];
    const float* e2 = eb2 + l*64;
    for (int m = 0; m < 64; ++m) s += e2[m] * Bm[m*64 + t];
    bfold[l*64 + t] = s;
  }
}

// ---------------- prep: pack weights as A-fragments of W^T (bf16) ----------
// wpk (shorts): [0,2048) embed (K=16 pad 32)
//   per layer l at 2048 + l*20480: +0 E1(K=128) +8192 N1'(K=128: Wn1a|Wfold) +16384 N2(K=64)
//   ro_w1 at 63488 (K=64). total 67584 shorts.
// frag(ks,mt,lane,e) = W[ks*32 + (lane>>4)*8 + e][mt*16 + (lane&15)]
__global__ void prep_pack(const float* __restrict__ embw,
                          const float* __restrict__ ew1,
                          const float* __restrict__ nw1,
                          const float* __restrict__ nw2,
                          const float* __restrict__ row1,
                          const float* __restrict__ wfold,
                          short* __restrict__ wpk)
{
  int tid = blockIdx.x*256 + threadIdx.x;
  if (tid >= 67584) return;
  int rem; const float* Wa; const float* Wb = nullptr; int Kact;
  if (tid < 2048){ rem = tid; Wa = embw; Kact = 16; }
  else if (tid < 63488){
    int t2 = tid - 2048, li = t2/20480, r = t2%20480;
    if (r < 8192)       { rem = r;         Wa = ew1 + li*8192; Wb = Wa + 4096;        Kact = 128; }
    else if (r < 16384) { rem = r - 8192;  Wa = nw1 + li*8192; Wb = wfold + li*4096;  Kact = 128; }
    else                { rem = r - 16384; Wa = nw2 + li*4096;                         Kact = 64; }
  } else { rem = tid - 63488; Wa = row1; Kact = 64; }
  int e = rem & 7, lane = (rem >> 3) & 63, mt = (rem >> 9) & 3, ks = rem >> 11;
  int k = ks*32 + (lane >> 4)*8 + e;
  int col = mt*16 + (lane & 15);
  float v = 0.f;
  if (k < Kact) v = (k < 64) ? Wa[k*64 + col] : Wb[(k - 64)*64 + col];
  wpk[tid] = f2bf(v);
}

// pack ro_w2 with output channel-permutation folded in, plus permuted bias.
__global__ void prep_w2(const float* __restrict__ ro_w2, const float* __restrict__ ro_b2,
                        short* __restrict__ w2p, float* __restrict__ b2p)
{
  int tid = blockIdx.x * 256 + threadIdx.x;
  if (tid < 633856){
    int e = tid & 7, lane = (tid >> 3) & 63, ks = (tid >> 9) & 1, nt = tid >> 10;
    int k = ks*32 + (lane >> 4)*8 + e;
    int p = nt*16 + (lane & 15);
    float v = 0.f;
    if (p < 9900){ int c = p / 900, rm = p % 900; v = ro_w2[k*9900 + rm*11 + c]; }
    w2p[tid] = f2bf(v);
  } else if (tid < 633856 + 9904){
    int p = tid - 633856;
    float v = 0.f;
    if (p < 9900){ int c = p / 900, rm = p % 900; v = ro_b2[rm*11 + c]; }
    b2p[p] = v;
  }
}

// ---------------- phase A: transposed chain; one wave == one batch ----------
__global__ __launch_bounds__(256) void gnn_phaseA(
    const float* __restrict__ nf, const int* __restrict__ nn,
    const float* __restrict__ embb,
    const float* __restrict__ eb1, const float* __restrict__ nb2,
    const float* __restrict__ lng, const float* __restrict__ lnb,
    const short* __restrict__ wpk, const float* __restrict__ bfold,
    short* __restrict__ gvb)
{
  __shared__ short lds[4][4160];   // per wave: h 2048 | buf 2048 | mm 64
  const int wave = threadIdx.x >> 6, lane = threadIdx.x & 63;
  const int l15 = lane & 15, lg = lane >> 4;
  const int b = blockIdx.x * 4 + wave;
  short* hs  = &lds[wave][0];
  short* buf = &lds[wave][2048];
  short* mms = &lds[wave][4096];
  const int n = nn[b];
  const float cinv = 1.0f / (float)(n < 1 ? 1 : n);
  const bool keep0 = l15 < n, keep1 = (16 + l15) < n;
  const int fb = lg*4;                 // lane's feature base inside an mt tile
  const int sw = (l15 & 7) << 3;       // XOR swizzle (shorts)
  const int rb0 = l15*64, rb1 = (16 + l15)*64;

  float hD[4][2][4];                   // h^T residual stream, fp32 D-layout
  f32x4 acc[4][2];
  float cs[4][4];

  // ---- embed: h0^T = (nf @ embW)^T + b, masked ----
  {
    bf16x8 bfr[2];
#pragma unroll
    for (int nt = 0; nt < 2; ++nt){
      int node = nt*16 + l15;
      bf16x8 a;
#pragma unroll
      for (int e = 0; e < 8; ++e) a[e] = 0;
      if (lg < 2 && node < 20){
        const float* s = nf + (b*20 + node)*16 + lg*8;
        float4 s0 = *(const float4*)(s);
        float4 s1 = *(const float4*)(s + 4);
        union { bf16x8 v; uint32_t u[4]; } q;
        q.u[0] = pk2(s0.x, s0.y); q.u[1] = pk2(s0.z, s0.w);
        q.u[2] = pk2(s1.x, s1.y); q.u[3] = pk2(s1.z, s1.w);
        a = q.v;
      }
      bfr[nt] = a;
    }
#pragma unroll
    for (int mt = 0; mt < 4; ++mt){
      bf16x8 af = *(const bf16x8*)(wpk + (mt*64 + lane)*8);
      f32x4 z = {0.f,0.f,0.f,0.f};
      acc[mt][0] = mfma16(af, bfr[0], z);
      acc[mt][1] = mfma16(af, bfr[1], z);
    }
#pragma unroll
    for (int mt = 0; mt < 4; ++mt){
      float4 bias = *(const float4*)(embb + mt*16 + fb);
#pragma unroll
      for (int nt = 0; nt < 2; ++nt){
        bool kp = nt ? keep1 : keep0;
#pragma unroll
        for (int e = 0; e < 4; ++e){
          float v = acc[mt][nt][e] + ((const float*)&bias)[e];
          hD[mt][nt][e] = kp ? v : 0.f;
        }
        int base = nt ? rb1 : rb0;
        uint32_t w0 = pk2(hD[mt][nt][0], hD[mt][nt][1]);
        uint32_t w1 = pk2(hD[mt][nt][2], hD[mt][nt][3]);
        *(uint2*)&hs[base + ((mt*16 + fb) ^ sw)] = make_uint2(w0, w1);
      }
#pragma unroll
      for (int e = 0; e < 4; ++e){
        float c = hD[mt][0][e] + hD[mt][1][e];
        c += __shfl_xor(c, 1); c += __shfl_xor(c, 2);
        c += __shfl_xor(c, 4); c += __shfl_xor(c, 8);
        cs[mt][e] = c * cinv;
      }
    }
    if (l15 == 0){
#pragma unroll
      for (int mt = 0; mt < 4; ++mt)
        *(uint2*)&mms[mt*16 + fb] = make_uint2(pk2(cs[mt][0], cs[mt][1]),
                                               pk2(cs[mt][2], cs[mt][3]));
    }
  }

  // ---- 3 layers: E1 -> N1' -> N2(+LN) ----
  for (int li = 0; li < 3; ++li){
    const short* wl = wpk + 2048 + li*20480;

    // E1: (edge_in @ We1)^T, K=128 (h | mm)
#pragma unroll
    for (int mt = 0; mt < 4; ++mt){ acc[mt][0] = (f32x4){0.f,0.f,0.f,0.f}; acc[mt][1] = (f32x4){0.f,0.f,0.f,0.f}; }
#pragma unroll
    for (int ks = 0; ks < 4; ++ks){
      bf16x8 bfr0, bfr1;
      if (ks < 2){
        int ko = (ks*32 + lg*8) ^ sw;
        bfr0 = *(const bf16x8*)&hs[rb0 + ko];
        bfr1 = *(const bf16x8*)&hs[rb1 + ko];
      } else {
        bfr0 = *(const bf16x8*)&mms[(ks - 2)*32 + lg*8];
        bfr1 = bfr0;
      }
#pragma unroll
      for (int mt = 0; mt < 4; ++mt){
        bf16x8 af = *(const bf16x8*)(wl + ((ks*4 + mt)*64 + lane)*8);
        acc[mt][0] = mfma16(af, bfr0, acc[mt][0]);
        acc[mt][1] = mfma16(af, bfr1, acc[mt][1]);
      }
    }
#pragma unroll
    for (int mt = 0; mt < 4; ++mt){
      float4 bias = *(const float4*)(eb1 + li*64 + mt*16 + fb);
#pragma unroll
      for (int nt = 0; nt < 2; ++nt){
        float v0 = acc[mt][nt][0] + ((const float*)&bias)[0];
        float v1 = acc[mt][nt][1] + ((const float*)&bias)[1];
        float v2 = acc[mt][nt][2] + ((const float*)&bias)[2];
        float v3 = acc[mt][nt][3] + ((const float*)&bias)[3];
        v0 = v0 > 0.f ? v0 : 0.f; v1 = v1 > 0.f ? v1 : 0.f;
        v2 = v2 > 0.f ? v2 : 0.f; v3 = v3 > 0.f ? v3 : 0.f;
        int base = nt ? rb1 : rb0;
        *(uint2*)&buf[base + ((mt*16 + fb) ^ sw)] = make_uint2(pk2(v0, v1), pk2(v2, v3));
      }
    }

    // N1': (node_in @ [Wn1a|Wfold])^T, K=128 (h | A1)
#pragma unroll
    for (int mt = 0; mt < 4; ++mt){ acc[mt][0] = (f32x4){0.f,0.f,0.f,0.f}; acc[mt][1] = (f32x4){0.f,0.f,0.f,0.f}; }
#pragma unroll
    for (int ks = 0; ks < 4; ++ks){
      const short* src = (ks < 2) ? hs : buf;
      int ko = (((ks & 1)*32) + lg*8) ^ sw;
      bf16x8 bfr0 = *(const bf16x8*)&src[rb0 + ko];
      bf16x8 bfr1 = *(const bf16x8*)&src[rb1 + ko];
#pragma unroll
      for (int mt = 0; mt < 4; ++mt){
        bf16x8 af = *(const bf16x8*)(wl + 8192 + ((ks*4 + mt)*64 + lane)*8);
        acc[mt][0] = mfma16(af, bfr0, acc[mt][0]);
        acc[mt][1] = mfma16(af, bfr1, acc[mt][1]);
      }
    }
#pragma unroll
    for (int mt = 0; mt < 4; ++mt){
      float4 bias = *(const float4*)(bfold + li*64 + mt*16 + fb);
#pragma unroll
      for (int nt = 0; nt < 2; ++nt){
        float v0 = acc[mt][nt][0] + ((const float*)&bias)[0];
        float v1 = acc[mt][nt][1] + ((const float*)&bias)[1];
        float v2 = acc[mt][nt][2] + ((const float*)&bias)[2];
        float v3 = acc[mt][nt][3] + ((const float*)&bias)[3];
        v0 = v0 > 0.f ? v0 : 0.f; v1 = v1 > 0.f ? v1 : 0.f;
        v2 = v2 > 0.f ? v2 : 0.f; v3 = v3 > 0.f ? v3 : 0.f;
        int base = nt ? rb1 : rb0;
        *(uint2*)&buf[base + ((mt*16 + fb) ^ sw)] = make_uint2(pk2(v0, v1), pk2(v2, v3));
      }
    }

    // N2: K=64 from buf; h = mask(LN(h + .))
#pragma unroll
    for (int mt = 0; mt < 4; ++mt){ acc[mt][0] = (f32x4){0.f,0.f,0.f,0.f}; acc[mt][1] = (f32x4){0.f,0.f,0.f,0.f}; }
#pragma unroll
    for (int ks = 0; ks < 2; ++ks){
      int ko = (ks*32 + lg*8) ^ sw;
      bf16x8 bfr0 = *(const bf16x8*)&buf[rb0 + ko];
      bf16x8 bfr1 = *(const bf16x8*)&buf[rb1 + ko];
#pragma unroll
      for (int mt = 0; mt < 4; ++mt){
        bf16x8 af = *(const bf16x8*)(wl + 16384 + ((ks*4 + mt)*64 + lane)*8);
        acc[mt][0] = mfma16(af, bfr0, acc[mt][0]);
        acc[mt][1] = mfma16(af, bfr1, acc[mt][1]);
      }
    }
    float s1a = 0.f, s2a = 0.f, s1b = 0.f, s2b = 0.f;
#pragma unroll
    for (int mt = 0; mt < 4; ++mt){
      float4 bias = *(const float4*)(nb2 + li*64 + mt*16 + fb);
#pragma unroll
      for (int e = 0; e < 4; ++e){
        float va = hD[mt][0][e] + acc[mt][0][e] + ((const float*)&bias)[e];
        float vb = hD[mt][1][e] + acc[mt][1][e] + ((const float*)&bias)[e];
        hD[mt][0][e] = va; hD[mt][1][e] = vb;
        s1a += va; s2a += va*va; s1b += vb; s2b += vb*vb;
      }
    }
    s1a += __shfl_xor(s1a, 16); s1a += __shfl_xor(s1a, 32);
    s2a += __shfl_xor(s2a, 16); s2a += __shfl_xor(s2a, 32);
    s1b += __shfl_xor(s1b, 16); s1b += __shfl_xor(s1b, 32);
    s2b += __shfl_xor(s2b, 16); s2b += __shfl_xor(s2b, 32);
    float meana = s1a * 0.015625f, meanb = s1b * 0.015625f;
    float rstda = rsqrtf(s2a * 0.015625f - meana*meana + 1e-5f);
    float rstdb = rsqrtf(s2b * 0.015625f - meanb*meanb + 1e-5f);
#pragma unroll
    for (int mt = 0; mt < 4; ++mt){
      float4 g = *(const float4*)(lng + li*64 + mt*16 + fb);
      float4 bb = *(const float4*)(lnb + li*64 + mt*16 + fb);
#pragma unroll
      for (int e = 0; e < 4; ++e){
        float ge = ((const float*)&g)[e], be = ((const float*)&bb)[e];
        float ya = (hD[mt][0][e] - meana) * rstda * ge + be;
        float yb = (hD[mt][1][e] - meanb) * rstdb * ge + be;
        ya = keep0 ? ya : 0.f;
        yb = keep1 ? yb : 0.f;
        hD[mt][0][e] = ya; hD[mt][1][e] = yb;
        cs[mt][e] = ya + yb;
      }
      *(uint2*)&hs[rb0 + ((mt*16 + fb) ^ sw)] =
          make_uint2(pk2(hD[mt][0][0], hD[mt][0][1]), pk2(hD[mt][0][2], hD[mt][0][3]));
      *(uint2*)&hs[rb1 + ((mt*16 + fb) ^ sw)] =
          make_uint2(pk2(hD[mt][1][0], hD[mt][1][1]), pk2(hD[mt][1][2], hD[mt][1][3]));
    }
#pragma unroll
    for (int mt = 0; mt < 4; ++mt)
#pragma unroll
      for (int e = 0; e < 4; ++e){
        float c = cs[mt][e];
        c += __shfl_xor(c, 1); c += __shfl_xor(c, 2);
        c += __shfl_xor(c, 4); c += __shfl_xor(c, 8);
        cs[mt][e] = c * cinv;
      }
    if (l15 == 0){
      if (li < 2){
#pragma unroll
        for (int mt = 0; mt < 4; ++mt)
          *(uint2*)&mms[mt*16 + fb] = make_uint2(pk2(cs[mt][0], cs[mt][1]),
                                                 pk2(cs[mt][2], cs[mt][3]));
      } else {
#pragma unroll
        for (int mt = 0; mt < 4; ++mt)
          *(uint2*)(gvb + b*64 + mt*16 + fb) = make_uint2(pk2(cs[mt][0], cs[mt][1]),
                                                          pk2(cs[mt][2], cs[mt][3]));
      }
    }
  }
}

// ---------------- phase B: out = relu(gv@ro_w1+b1) @ w2p + b2p (store-bound) ---
__global__ __launch_bounds__(256) void gnn_phaseB(
    const short* __restrict__ gvb, const float* __restrict__ rb1,
    const short* __restrict__ wro1, const short* __restrict__ w2p,
    const float* __restrict__ b2p, float* __restrict__ out)
{
  __shared__ short tl[4][1024];
  const int wave = threadIdx.x >> 6, lane = threadIdx.x & 63;
  const int l15 = lane & 15, lg = lane >> 4;
  const int b0 = blockIdx.x * 64 + wave * 16;

  f32x4 tacc[4];
#pragma unroll
  for (int nt = 0; nt < 4; ++nt) tacc[nt] = (f32x4){0.f,0.f,0.f,0.f};
#pragma unroll
  for (int ks = 0; ks < 2; ++ks){
    bf16x8 a = *(const bf16x8*)&gvb[(b0 + l15)*64 + ks*32 + lg*8];
#pragma unroll
    for (int nt = 0; nt < 4; ++nt){
      bf16x8 bq = *(const bf16x8*)(wro1 + ((ks*4 + nt)*64 + lane)*8);
      tacc[nt] = mfma16(a, bq, tacc[nt]);
    }
  }
  short* tw = tl[wave];
#pragma unroll
  for (int nt = 0; nt < 4; ++nt){
    float bias = rb1[nt*16 + l15];
#pragma unroll
    for (int e = 0; e < 4; ++e){
      int row = lg*4 + e;
      float v = tacc[nt][e] + bias;
      v = v > 0.f ? v : 0.f;
      tw[((row*64) + (nt*16 + l15)) ^ ((row & 7) << 3)] = f2bf(v);
    }
  }
  bf16x8 ta0 = *(const bf16x8*)&tw[((l15*64) + (lg*8))      ^ ((l15 & 7) << 3)];
  bf16x8 ta1 = *(const bf16x8*)&tw[((l15*64) + (32 + lg*8)) ^ ((l15 & 7) << 3)];

  const int nt0 = blockIdx.y * 124;
  const int nt1 = (nt0 + 124 < 619) ? nt0 + 124 : 619;
  for (int nt = nt0; nt < nt1; ++nt){
    const bf16x8* wp = (const bf16x8*)w2p + nt*128;
    f32x4 c = (f32x4){0.f,0.f,0.f,0.f};
    c = mfma16(ta0, wp[lane], c);
    c = mfma16(ta1, wp[64 + lane], c);
    int p = nt*16 + l15;
    if (p < 9900){
      float bias = b2p[p];
      float* o = out + (size_t)(b0 + lg*4)*9900 + p;
#pragma unroll
      for (int e = 0; e < 4; ++e) o[(size_t)e*9900] = c[e] + bias;
    }
  }
}

extern "C" void kernel_launch(void* const* d_in, const int* in_sizes, int n_in,
                              void* d_out, int out_size, void* d_ws, size_t ws_size,
                              hipStream_t stream)
{
  const float* nf   = (const float*)d_in[0];
  const int*   nn   = (const int*)d_in[1];
  const float* embw = (const float*)d_in[2];
  const float* embb = (const float*)d_in[3];
  const float* ew1  = (const float*)d_in[4];
  const float* eb1  = (const float*)d_in[5];
  const float* ew2  = (const float*)d_in[6];
  const float* eb2  = (const float*)d_in[7];
  const float* nw1  = (const float*)d_in[8];
  const float* nb1  = (const float*)d_in[9];
  const float* nw2  = (const float*)d_in[10];
  const float* nb2  = (const float*)d_in[11];
  const float* lng  = (const float*)d_in[12];
  const float* lnb  = (const float*)d_in[13];
  const float* rw1  = (const float*)d_in[14];
  const float* rb1  = (const float*)d_in[15];
  const float* rw2  = (const float*)d_in[16];
  const float* rb2  = (const float*)d_in[17];
  float* out = (float*)d_out;

  const int B = in_sizes[0] / 320;   // 16384

  char* ws = (char*)d_ws;
  short* gvb  = (short*)ws;                    // B*64 bf16 = 2,097,152 B
  float* b2p  = (float*)(ws + 2097152);        // 9904 f32
  float* wfold= (float*)(ws + 2136768);        // 3*4096 f32
  float* bfold= (float*)(ws + 2185920);        // 3*64 f32
  short* wpk  = (short*)(ws + 2186688);        // 67584 shorts
  short* w2p  = (short*)(ws + 2321856);        // 633856 shorts (end ~3.59 MB)

  prep_fold<<<3, 256, 0, stream>>>(ew2, eb2, nw1, nb1, wfold, bfold);
  prep_pack<<<(67584 + 255)/256, 256, 0, stream>>>(embw, ew1, nw1, nw2, rw1, wfold, wpk);
  prep_w2<<<(633856 + 9904 + 255)/256, 256, 0, stream>>>(rw2, rb2, w2p, b2p);
  gnn_phaseA<<<B/4, 256, 0, stream>>>(nf, nn, embb, eb1, nb2, lng, lnb, wpk, bfold, gvb);
  gnn_phaseB<<<dim3(B/64, 5), 256, 0, stream>>>(gvb, rb1, wpk + 63488, w2p, b2p, out);
}

// Round 4
// 493.080 us; speedup vs baseline: 1.0459x; 1.0459x over previous
//
#include <hip/hip_runtime.h>
#include <hip/hip_bf16.h>
#include <stdint.h>

typedef __attribute__((ext_vector_type(8))) short bf16x8;
typedef __attribute__((ext_vector_type(4))) float f32x4;

// explicit round-to-nearest-even f32 -> bf16
__device__ __forceinline__ uint32_t f2bfu(float x){
  union { float f; uint32_t u; } v; v.f = x;
  return (v.u + 0x7FFFu + ((v.u >> 16) & 1u)) >> 16;
}
__device__ __forceinline__ short f2bf(float x){ return (short)(uint16_t)f2bfu(x); }
// pack two f32 -> u32 of 2 bf16, RNE (lo = a, hi = b)
__device__ __forceinline__ uint32_t pk2(float a, float b){
  return (f2bfu(a) & 0xFFFFu) | (f2bfu(b) << 16);
}

__device__ __forceinline__ f32x4 mfma16(bf16x8 a, bf16x8 b, f32x4 c){
  return __builtin_amdgcn_mfma_f32_16x16x32_bf16(a, b, c, 0, 0, 0);
}

// ---------------- prep: fold E2 into N1 -----------------------------------
// Wfold[l] = We2[l] @ Wn1[l][64:128]  (64x64, fp32)
// bfold[l] = nb1[l] + eb2[l] @ Wn1[l][64:128]
__global__ void prep_fold(const float* __restrict__ ew2, const float* __restrict__ eb2,
                          const float* __restrict__ nw1, const float* __restrict__ nb1,
                          float* __restrict__ wfold, float* __restrict__ bfold)
{
  int l = blockIdx.x, t = threadIdx.x;
  const float* A  = ew2 + l*4096;            // We2 [64][64]
  const float* Bm = nw1 + l*8192 + 4096;     // Wn1b [64][64]
  for (int i = 0; i < 16; ++i){
    int idx = t + i*256;
    int r = idx >> 6, c = idx & 63;
    float s = 0.f;
    for (int m = 0; m < 64; ++m) s += A[r*64 + m] * Bm[m*64 + c];
    wfold[l*4096 + idx] = s;
  }
  if (t < 64){
    float s = nb1[l*64 + t];
    const float* e2 = eb2 + l*64;
    for (int m = 0; m < 64; ++m) s += e2[m] * Bm[m*64 + t];
    bfold[l*64 + t] = s;
  }
}

// ---------------- prep: pack weights as A-fragments of W^T (bf16) ----------
// wpk (shorts): [0,2048) embed (K=16 pad 32)
//   per layer l at 2048 + l*20480: +0 E1(K=128) +8192 N1'(K=128: Wn1a|Wfold) +16384 N2(K=64)
//   ro_w1 at 63488 (K=64). total 67584 shorts.
// frag(ks,mt,lane,e) = W[ks*32 + (lane>>4)*8 + e][mt*16 + (lane&15)]
__global__ void prep_pack(const float* __restrict__ embw,
                          const float* __restrict__ ew1,
                          const float* __restrict__ nw1,
                          const float* __restrict__ nw2,
                          const float* __restrict__ row1,
                          const float* __restrict__ wfold,
                          short* __restrict__ wpk)
{
  int tid = blockIdx.x*256 + threadIdx.x;
  if (tid >= 67584) return;
  int rem; const float* Wa; const float* Wb = nullptr; int Kact;
  if (tid < 2048){ rem = tid; Wa = embw; Kact = 16; }
  else if (tid < 63488){
    int t2 = tid - 2048, li = t2/20480, r = t2%20480;
    if (r < 8192)       { rem = r;         Wa = ew1 + li*8192; Wb = Wa + 4096;        Kact = 128; }
    else if (r < 16384) { rem = r - 8192;  Wa = nw1 + li*8192; Wb = wfold + li*4096;  Kact = 128; }
    else                { rem = r - 16384; Wa = nw2 + li*4096;                         Kact = 64; }
  } else { rem = tid - 63488; Wa = row1; Kact = 64; }
  int e = rem & 7, lane = (rem >> 3) & 63, mt = (rem >> 9) & 3, ks = rem >> 11;
  int k = ks*32 + (lane >> 4)*8 + e;
  int col = mt*16 + (lane & 15);
  float v = 0.f;
  if (k < Kact) v = (k < 64) ? Wa[k*64 + col] : Wb[(k - 64)*64 + col];
  wpk[tid] = f2bf(v);
}

// pack ro_w2 with output channel-permutation folded in AND the j-interleave for
// coalesced float4 stores. For column-group g (64 output cols) and MFMA j:
//   frag col c -> output-linear p = g*64 + c*4 + j   (c = lane&15)
// w2p layout: [g(155)][j(4)][ks(2)][lane(64)][e(8)]  = 634880 shorts.
// b2p in natural output order (zero-padded to 9920).
__global__ void prep_w2(const float* __restrict__ ro_w2, const float* __restrict__ ro_b2,
                        short* __restrict__ w2p, float* __restrict__ b2p)
{
  int tid = blockIdx.x * 256 + threadIdx.x;
  if (tid < 634880){
    int e = tid & 7, lane = (tid >> 3) & 63, ks = (tid >> 9) & 1, j = (tid >> 10) & 3, g = tid >> 12;
    int k = ks*32 + (lane >> 4)*8 + e;
    int p = g*64 + (lane & 15)*4 + j;
    float v = 0.f;
    if (p < 9900){ int c = p / 900, rm = p % 900; v = ro_w2[k*9900 + rm*11 + c]; }
    w2p[tid] = f2bf(v);
  } else if (tid < 634880 + 9920){
    int p = tid - 634880;
    float v = 0.f;
    if (p < 9900){ int c = p / 900, rm = p % 900; v = ro_b2[rm*11 + c]; }
    b2p[p] = v;
  }
}

// ---------------- phase A: transposed chain; one wave == one batch ----------
__global__ __launch_bounds__(256) void gnn_phaseA(
    const float* __restrict__ nf, const int* __restrict__ nn,
    const float* __restrict__ embb,
    const float* __restrict__ eb1, const float* __restrict__ nb2,
    const float* __restrict__ lng, const float* __restrict__ lnb,
    const short* __restrict__ wpk, const float* __restrict__ bfold,
    short* __restrict__ gvb)
{
  __shared__ short lds[4][4160];   // per wave: h 2048 | buf 2048 | mm 64
  const int wave = threadIdx.x >> 6, lane = threadIdx.x & 63;
  const int l15 = lane & 15, lg = lane >> 4;
  const int b = blockIdx.x * 4 + wave;
  short* hs  = &lds[wave][0];
  short* buf = &lds[wave][2048];
  short* mms = &lds[wave][4096];
  const int n = nn[b];
  const float cinv = 1.0f / (float)(n < 1 ? 1 : n);
  const bool keep0 = l15 < n, keep1 = (16 + l15) < n;
  const int fb = lg*4;                 // lane's feature base inside an mt tile
  const int sw = (l15 & 7) << 3;       // XOR swizzle (shorts)
  const int rb0 = l15*64, rb1 = (16 + l15)*64;

  float hD[4][2][4];                   // h^T residual stream, fp32 D-layout
  f32x4 acc[4][2];
  float cs[4][4];

  // ---- embed: h0^T = (nf @ embW)^T + b, masked ----
  {
    bf16x8 bfr[2];
#pragma unroll
    for (int nt = 0; nt < 2; ++nt){
      int node = nt*16 + l15;
      bf16x8 a;
#pragma unroll
      for (int e = 0; e < 8; ++e) a[e] = 0;
      if (lg < 2 && node < 20){
        const float* s = nf + (b*20 + node)*16 + lg*8;
        float4 s0 = *(const float4*)(s);
        float4 s1 = *(const float4*)(s + 4);
        union { bf16x8 v; uint32_t u[4]; } q;
        q.u[0] = pk2(s0.x, s0.y); q.u[1] = pk2(s0.z, s0.w);
        q.u[2] = pk2(s1.x, s1.y); q.u[3] = pk2(s1.z, s1.w);
        a = q.v;
      }
      bfr[nt] = a;
    }
#pragma unroll
    for (int mt = 0; mt < 4; ++mt){
      bf16x8 af = *(const bf16x8*)(wpk + (mt*64 + lane)*8);
      f32x4 z = {0.f,0.f,0.f,0.f};
      acc[mt][0] = mfma16(af, bfr[0], z);
      acc[mt][1] = mfma16(af, bfr[1], z);
    }
#pragma unroll
    for (int mt = 0; mt < 4; ++mt){
      float4 bias = *(const float4*)(embb + mt*16 + fb);
#pragma unroll
      for (int nt = 0; nt < 2; ++nt){
        bool kp = nt ? keep1 : keep0;
#pragma unroll
        for (int e = 0; e < 4; ++e){
          float v = acc[mt][nt][e] + ((const float*)&bias)[e];
          hD[mt][nt][e] = kp ? v : 0.f;
        }
        int base = nt ? rb1 : rb0;
        uint32_t w0 = pk2(hD[mt][nt][0], hD[mt][nt][1]);
        uint32_t w1 = pk2(hD[mt][nt][2], hD[mt][nt][3]);
        *(uint2*)&hs[base + ((mt*16 + fb) ^ sw)] = make_uint2(w0, w1);
      }
#pragma unroll
      for (int e = 0; e < 4; ++e){
        float c = hD[mt][0][e] + hD[mt][1][e];
        c += __shfl_xor(c, 1); c += __shfl_xor(c, 2);
        c += __shfl_xor(c, 4); c += __shfl_xor(c, 8);
        cs[mt][e] = c * cinv;
      }
    }
    if (l15 == 0){
#pragma unroll
      for (int mt = 0; mt < 4; ++mt)
        *(uint2*)&mms[mt*16 + fb] = make_uint2(pk2(cs[mt][0], cs[mt][1]),
                                               pk2(cs[mt][2], cs[mt][3]));
    }
  }

  // ---- 3 layers: E1 -> N1' -> N2(+LN) ----
  for (int li = 0; li < 3; ++li){
    const short* wl = wpk + 2048 + li*20480;

    // E1: (edge_in @ We1)^T, K=128 (h | mm)
#pragma unroll
    for (int mt = 0; mt < 4; ++mt){ acc[mt][0] = (f32x4){0.f,0.f,0.f,0.f}; acc[mt][1] = (f32x4){0.f,0.f,0.f,0.f}; }
#pragma unroll
    for (int ks = 0; ks < 4; ++ks){
      bf16x8 bfr0, bfr1;
      if (ks < 2){
        int ko = (ks*32 + lg*8) ^ sw;
        bfr0 = *(const bf16x8*)&hs[rb0 + ko];
        bfr1 = *(const bf16x8*)&hs[rb1 + ko];
      } else {
        bfr0 = *(const bf16x8*)&mms[(ks - 2)*32 + lg*8];
        bfr1 = bfr0;
      }
#pragma unroll
      for (int mt = 0; mt < 4; ++mt){
        bf16x8 af = *(const bf16x8*)(wl + ((ks*4 + mt)*64 + lane)*8);
        acc[mt][0] = mfma16(af, bfr0, acc[mt][0]);
        acc[mt][1] = mfma16(af, bfr1, acc[mt][1]);
      }
    }
#pragma unroll
    for (int mt = 0; mt < 4; ++mt){
      float4 bias = *(const float4*)(eb1 + li*64 + mt*16 + fb);
#pragma unroll
      for (int nt = 0; nt < 2; ++nt){
        float v0 = acc[mt][nt][0] + ((const float*)&bias)[0];
        float v1 = acc[mt][nt][1] + ((const float*)&bias)[1];
        float v2 = acc[mt][nt][2] + ((const float*)&bias)[2];
        float v3 = acc[mt][nt][3] + ((const float*)&bias)[3];
        v0 = v0 > 0.f ? v0 : 0.f; v1 = v1 > 0.f ? v1 : 0.f;
        v2 = v2 > 0.f ? v2 : 0.f; v3 = v3 > 0.f ? v3 : 0.f;
        int base = nt ? rb1 : rb0;
        *(uint2*)&buf[base + ((mt*16 + fb) ^ sw)] = make_uint2(pk2(v0, v1), pk2(v2, v3));
      }
    }

    // N1': (node_in @ [Wn1a|Wfold])^T, K=128 (h | A1)
#pragma unroll
    for (int mt = 0; mt < 4; ++mt){ acc[mt][0] = (f32x4){0.f,0.f,0.f,0.f}; acc[mt][1] = (f32x4){0.f,0.f,0.f,0.f}; }
#pragma unroll
    for (int ks = 0; ks < 4; ++ks){
      const short* src = (ks < 2) ? hs : buf;
      int ko = (((ks & 1)*32) + lg*8) ^ sw;
      bf16x8 bfr0 = *(const bf16x8*)&src[rb0 + ko];
      bf16x8 bfr1 = *(const bf16x8*)&src[rb1 + ko];
#pragma unroll
      for (int mt = 0; mt < 4; ++mt){
        bf16x8 af = *(const bf16x8*)(wl + 8192 + ((ks*4 + mt)*64 + lane)*8);
        acc[mt][0] = mfma16(af, bfr0, acc[mt][0]);
        acc[mt][1] = mfma16(af, bfr1, acc[mt][1]);
      }
    }
#pragma unroll
    for (int mt = 0; mt < 4; ++mt){
      float4 bias = *(const float4*)(bfold + li*64 + mt*16 + fb);
#pragma unroll
      for (int nt = 0; nt < 2; ++nt){
        float v0 = acc[mt][nt][0] + ((const float*)&bias)[0];
        float v1 = acc[mt][nt][1] + ((const float*)&bias)[1];
        float v2 = acc[mt][nt][2] + ((const float*)&bias)[2];
        float v3 = acc[mt][nt][3] + ((const float*)&bias)[3];
        v0 = v0 > 0.f ? v0 : 0.f; v1 = v1 > 0.f ? v1 : 0.f;
        v2 = v2 > 0.f ? v2 : 0.f; v3 = v3 > 0.f ? v3 : 0.f;
        int base = nt ? rb1 : rb0;
        *(uint2*)&buf[base + ((mt*16 + fb) ^ sw)] = make_uint2(pk2(v0, v1), pk2(v2, v3));
      }
    }

    // N2: K=64 from buf; h = mask(LN(h + .))
#pragma unroll
    for (int mt = 0; mt < 4; ++mt){ acc[mt][0] = (f32x4){0.f,0.f,0.f,0.f}; acc[mt][1] = (f32x4){0.f,0.f,0.f,0.f}; }
#pragma unroll
    for (int ks = 0; ks < 2; ++ks){
      int ko = (ks*32 + lg*8) ^ sw;
      bf16x8 bfr0 = *(const bf16x8*)&buf[rb0 + ko];
      bf16x8 bfr1 = *(const bf16x8*)&buf[rb1 + ko];
#pragma unroll
      for (int mt = 0; mt < 4; ++mt){
        bf16x8 af = *(const bf16x8*)(wl + 16384 + ((ks*4 + mt)*64 + lane)*8);
        acc[mt][0] = mfma16(af, bfr0, acc[mt][0]);
        acc[mt][1] = mfma16(af, bfr1, acc[mt][1]);
      }
    }
    float s1a = 0.f, s2a = 0.f, s1b = 0.f, s2b = 0.f;
#pragma unroll
    for (int mt = 0; mt < 4; ++mt){
      float4 bias = *(const float4*)(nb2 + li*64 + mt*16 + fb);
#pragma unroll
      for (int e = 0; e < 4; ++e){
        float va = hD[mt][0][e] + acc[mt][0][e] + ((const float*)&bias)[e];
        float vb = hD[mt][1][e] + acc[mt][1][e] + ((const float*)&bias)[e];
        hD[mt][0][e] = va; hD[mt][1][e] = vb;
        s1a += va; s2a += va*va; s1b += vb; s2b += vb*vb;
      }
    }
    s1a += __shfl_xor(s1a, 16); s1a += __shfl_xor(s1a, 32);
    s2a += __shfl_xor(s2a, 16); s2a += __shfl_xor(s2a, 32);
    s1b += __shfl_xor(s1b, 16); s1b += __shfl_xor(s1b, 32);
    s2b += __shfl_xor(s2b, 16); s2b += __shfl_xor(s2b, 32);
    float meana = s1a * 0.015625f, meanb = s1b * 0.015625f;
    float rstda = rsqrtf(s2a * 0.015625f - meana*meana + 1e-5f);
    float rstdb = rsqrtf(s2b * 0.015625f - meanb*meanb + 1e-5f);
#pragma unroll
    for (int mt = 0; mt < 4; ++mt){
      float4 g = *(const float4*)(lng + li*64 + mt*16 + fb);
      float4 bb = *(const float4*)(lnb + li*64 + mt*16 + fb);
#pragma unroll
      for (int e = 0; e < 4; ++e){
        float ge = ((const float*)&g)[e], be = ((const float*)&bb)[e];
        float ya = (hD[mt][0][e] - meana) * rstda * ge + be;
        float yb = (hD[mt][1][e] - meanb) * rstdb * ge + be;
        ya = keep0 ? ya : 0.f;
        yb = keep1 ? yb : 0.f;
        hD[mt][0][e] = ya; hD[mt][1][e] = yb;
        cs[mt][e] = ya + yb;
      }
      *(uint2*)&hs[rb0 + ((mt*16 + fb) ^ sw)] =
          make_uint2(pk2(hD[mt][0][0], hD[mt][0][1]), pk2(hD[mt][0][2], hD[mt][0][3]));
      *(uint2*)&hs[rb1 + ((mt*16 + fb) ^ sw)] =
          make_uint2(pk2(hD[mt][1][0], hD[mt][1][1]), pk2(hD[mt][1][2], hD[mt][1][3]));
    }
#pragma unroll
    for (int mt = 0; mt < 4; ++mt)
#pragma unroll
      for (int e = 0; e < 4; ++e){
        float c = cs[mt][e];
        c += __shfl_xor(c, 1); c += __shfl_xor(c, 2);
        c += __shfl_xor(c, 4); c += __shfl_xor(c, 8);
        cs[mt][e] = c * cinv;
      }
    if (l15 == 0){
      if (li < 2){
#pragma unroll
        for (int mt = 0; mt < 4; ++mt)
          *(uint2*)&mms[mt*16 + fb] = make_uint2(pk2(cs[mt][0], cs[mt][1]),
                                                 pk2(cs[mt][2], cs[mt][3]));
      } else {
#pragma unroll
        for (int mt = 0; mt < 4; ++mt)
          *(uint2*)(gvb + b*64 + mt*16 + fb) = make_uint2(pk2(cs[mt][0], cs[mt][1]),
                                                          pk2(cs[mt][2], cs[mt][3]));
      }
    }
  }
}

// ---------------- phase B: out = relu(gv@ro_w1+b1) @ w2p + b2p --------------
// j-interleaved w2p => each lane stores float4 (256B contiguous per 16-lane
// group, 16B aligned); consecutive g of the same wave are adjacent 256B.
__global__ __launch_bounds__(256) void gnn_phaseB(
    const short* __restrict__ gvb, const float* __restrict__ rb1,
    const short* __restrict__ wro1, const short* __restrict__ w2p,
    const float* __restrict__ b2p, float* __restrict__ out)
{
  __shared__ short tl[4][1024];
  const int wave = threadIdx.x >> 6, lane = threadIdx.x & 63;
  const int l15 = lane & 15, lg = lane >> 4;
  const int b0 = blockIdx.x * 64 + wave * 16;

  f32x4 tacc[4];
#pragma unroll
  for (int nt = 0; nt < 4; ++nt) tacc[nt] = (f32x4){0.f,0.f,0.f,0.f};
#pragma unroll
  for (int ks = 0; ks < 2; ++ks){
    bf16x8 a = *(const bf16x8*)&gvb[(b0 + l15)*64 + ks*32 + lg*8];
#pragma unroll
    for (int nt = 0; nt < 4; ++nt){
      bf16x8 bq = *(const bf16x8*)(wro1 + ((ks*4 + nt)*64 + lane)*8);
      tacc[nt] = mfma16(a, bq, tacc[nt]);
    }
  }
  short* tw = tl[wave];
#pragma unroll
  for (int nt = 0; nt < 4; ++nt){
    float bias = rb1[nt*16 + l15];
#pragma unroll
    for (int e = 0; e < 4; ++e){
      int row = lg*4 + e;
      float v = tacc[nt][e] + bias;
      v = v > 0.f ? v : 0.f;
      tw[((row*64) + (nt*16 + l15)) ^ ((row & 7) << 3)] = f2bf(v);
    }
  }
  bf16x8 ta0 = *(const bf16x8*)&tw[((l15*64) + (lg*8))      ^ ((l15 & 7) << 3)];
  bf16x8 ta1 = *(const bf16x8*)&tw[((l15*64) + (32 + lg*8)) ^ ((l15 & 7) << 3)];

  const int g0 = blockIdx.y * 31;
  const int g1 = (g0 + 31 < 155) ? g0 + 31 : 155;
  for (int g = g0; g < g1; ++g){
    const bf16x8* wp = (const bf16x8*)w2p + g*512;   // [j(4)][ks(2)][lane(64)]
    f32x4 c[4];
#pragma unroll
    for (int j = 0; j < 4; ++j){
      f32x4 z = {0.f,0.f,0.f,0.f};
      z = mfma16(ta0, wp[(j*2 + 0)*64 + lane], z);
      c[j] = mfma16(ta1, wp[(j*2 + 1)*64 + lane], z);
    }
    int p0 = g*64 + l15*4;
    if (p0 < 9900){
      float4 bias = *(const float4*)(b2p + p0);
      float* o = out + (size_t)(b0 + lg*4)*9900 + p0;
#pragma unroll
      for (int e = 0; e < 4; ++e){
        float4 o4 = make_float4(c[0][e] + bias.x, c[1][e] + bias.y,
                                c[2][e] + bias.z, c[3][e] + bias.w);
        *(float4*)(o + (size_t)e*9900) = o4;
      }
    }
  }
}

extern "C" void kernel_launch(void* const* d_in, const int* in_sizes, int n_in,
                              void* d_out, int out_size, void* d_ws, size_t ws_size,
                              hipStream_t stream)
{
  const float* nf   = (const float*)d_in[0];
  const int*   nn   = (const int*)d_in[1];
  const float* embw = (const float*)d_in[2];
  const float* embb = (const float*)d_in[3];
  const float* ew1  = (const float*)d_in[4];
  const float* eb1  = (const float*)d_in[5];
  const float* ew2  = (const float*)d_in[6];
  const float* eb2  = (const float*)d_in[7];
  const float* nw1  = (const float*)d_in[8];
  const float* nb1  = (const float*)d_in[9];
  const float* nw2  = (const float*)d_in[10];
  const float* nb2  = (const float*)d_in[11];
  const float* lng  = (const float*)d_in[12];
  const float* lnb  = (const float*)d_in[13];
  const float* rw1  = (const float*)d_in[14];
  const float* rb1  = (const float*)d_in[15];
  const float* rw2  = (const float*)d_in[16];
  const float* rb2  = (const float*)d_in[17];
  float* out = (float*)d_out;

  const int B = in_sizes[0] / 320;   // 16384

  char* ws = (char*)d_ws;
  short* gvb  = (short*)ws;                    // B*64 bf16 = 2,097,152 B
  float* b2p  = (float*)(ws + 2097152);        // 9920 f32   (end 2,136,832)
  float* wfold= (float*)(ws + 2136832);        // 3*4096 f32 (end 2,185,984)
  float* bfold= (float*)(ws + 2185984);        // 3*64 f32   (end 2,186,752)
  short* wpk  = (short*)(ws + 2186752);        // 67584 sh   (end 2,321,920)
  short* w2p  = (short*)(ws + 2321920);        // 634880 sh  (end 3,591,680)

  prep_fold<<<3, 256, 0, stream>>>(ew2, eb2, nw1, nb1, wfold, bfold);
  prep_pack<<<(67584 + 255)/256, 256, 0, stream>>>(embw, ew1, nw1, nw2, rw1, wfold, wpk);
  prep_w2<<<(634880 + 9920 + 255)/256, 256, 0, stream>>>(rw2, rb2, w2p, b2p);
  gnn_phaseA<<<B/4, 256, 0, stream>>>(nf, nn, embb, eb1, nb2, lng, lnb, wpk, bfold, gvb);
  gnn_phaseB<<<dim3(B/64, 5), 256, 0, stream>>>(gvb, rb1, wpk + 63488, w2p, b2p, out);
}

// Round 5
// 485.836 us; speedup vs baseline: 1.0615x; 1.0149x over previous
//
#include <hip/hip_runtime.h>
#include <hip/hip_bf16.h>
#include <stdint.h>

typedef __attribute__((ext_vector_type(8))) short bf16x8;
typedef __attribute__((ext_vector_type(4))) float f32x4;

// explicit round-to-nearest-even f32 -> bf16
__device__ __forceinline__ uint32_t f2bfu(float x){
  union { float f; uint32_t u; } v; v.f = x;
  return (v.u + 0x7FFFu + ((v.u >> 16) & 1u)) >> 16;
}
__device__ __forceinline__ short f2bf(float x){ return (short)(uint16_t)f2bfu(x); }
// pack two f32 -> u32 of 2 bf16, RNE (lo = a, hi = b)
__device__ __forceinline__ uint32_t pk2(float a, float b){
  return (f2bfu(a) & 0xFFFFu) | (f2bfu(b) << 16);
}

__device__ __forceinline__ f32x4 mfma16(bf16x8 a, bf16x8 b, f32x4 c){
  return __builtin_amdgcn_mfma_f32_16x16x32_bf16(a, b, c, 0, 0, 0);
}

// ---------------- prep: fold E2 into N1 -----------------------------------
// Wfold[l] = We2[l] @ Wn1[l][64:128]  (64x64, fp32)
// bfold[l] = nb1[l] + eb2[l] @ Wn1[l][64:128]
__global__ void prep_fold(const float* __restrict__ ew2, const float* __restrict__ eb2,
                          const float* __restrict__ nw1, const float* __restrict__ nb1,
                          float* __restrict__ wfold, float* __restrict__ bfold)
{
  int l = blockIdx.x, t = threadIdx.x;
  const float* A  = ew2 + l*4096;            // We2 [64][64]
  const float* Bm = nw1 + l*8192 + 4096;     // Wn1b [64][64]
  for (int i = 0; i < 16; ++i){
    int idx = t + i*256;
    int r = idx >> 6, c = idx & 63;
    float s = 0.f;
    for (int m = 0; m < 64; ++m) s += A[r*64 + m] * Bm[m*64 + c];
    wfold[l*4096 + idx] = s;
  }
  if (t < 64){
    float s = nb1[l*64 + t];
    const float* e2 = eb2 + l*64;
    for (int m = 0; m < 64; ++m) s += e2[m] * Bm[m*64 + t];
    bfold[l*64 + t] = s;
  }
}

// ---------------- prep: pack weights as A-fragments of W^T (bf16) ----------
// wpk (shorts): [0,2048) embed (K=16 pad 32)
//   per layer l at 2048 + l*20480: +0 E1(K=128) +8192 N1'(K=128: Wn1a|Wfold) +16384 N2(K=64)
//   ro_w1 at 63488 (K=64). total 67584 shorts.
// frag(ks,mt,lane,e) = W[ks*32 + (lane>>4)*8 + e][mt*16 + (lane&15)]
__global__ void prep_pack(const float* __restrict__ embw,
                          const float* __restrict__ ew1,
                          const float* __restrict__ nw1,
                          const float* __restrict__ nw2,
                          const float* __restrict__ row1,
                          const float* __restrict__ wfold,
                          short* __restrict__ wpk)
{
  int tid = blockIdx.x*256 + threadIdx.x;
  if (tid >= 67584) return;
  int rem; const float* Wa; const float* Wb = nullptr; int Kact;
  if (tid < 2048){ rem = tid; Wa = embw; Kact = 16; }
  else if (tid < 63488){
    int t2 = tid - 2048, li = t2/20480, r = t2%20480;
    if (r < 8192)       { rem = r;         Wa = ew1 + li*8192; Wb = Wa + 4096;        Kact = 128; }
    else if (r < 16384) { rem = r - 8192;  Wa = nw1 + li*8192; Wb = wfold + li*4096;  Kact = 128; }
    else                { rem = r - 16384; Wa = nw2 + li*4096;                         Kact = 64; }
  } else { rem = tid - 63488; Wa = row1; Kact = 64; }
  int e = rem & 7, lane = (rem >> 3) & 63, mt = (rem >> 9) & 3, ks = rem >> 11;
  int k = ks*32 + (lane >> 4)*8 + e;
  int col = mt*16 + (lane & 15);
  float v = 0.f;
  if (k < Kact) v = (k < 64) ? Wa[k*64 + col] : Wb[(k - 64)*64 + col];
  wpk[tid] = f2bf(v);
}

// pack ro_w2 with output channel-permutation folded in AND the j-interleave for
// coalesced float4 stores. For column-group g (64 output cols) and MFMA j:
//   frag col c -> output-linear p = g*64 + c*4 + j   (c = lane&15)
// w2p layout: [g(155)][j(4)][ks(2)][lane(64)][e(8)]  = 634880 shorts.
// b2p in natural output order (zero-padded to 9920).
__global__ void prep_w2(const float* __restrict__ ro_w2, const float* __restrict__ ro_b2,
                        short* __restrict__ w2p, float* __restrict__ b2p)
{
  int tid = blockIdx.x * 256 + threadIdx.x;
  if (tid < 634880){
    int e = tid & 7, lane = (tid >> 3) & 63, ks = (tid >> 9) & 1, j = (tid >> 10) & 3, g = tid >> 12;
    int k = ks*32 + (lane >> 4)*8 + e;
    int p = g*64 + (lane & 15)*4 + j;
    float v = 0.f;
    if (p < 9900){ int c = p / 900, rm = p % 900; v = ro_w2[k*9900 + rm*11 + c]; }
    w2p[tid] = f2bf(v);
  } else if (tid < 634880 + 9920){
    int p = tid - 634880;
    float v = 0.f;
    if (p < 9900){ int c = p / 900, rm = p % 900; v = ro_b2[rm*11 + c]; }
    b2p[p] = v;
  }
}

// ---------------- phase A: transposed chain; one wave == one batch ----------
// 8 waves/block; per-stage __syncthreads() clusters the 8 waves' identical
// weight-fragment loads in time so L1 serves 7 of 8 (4x+ L2 traffic cut).
__global__ __launch_bounds__(512) void gnn_phaseA(
    const float* __restrict__ nf, const int* __restrict__ nn,
    const float* __restrict__ embb,
    const float* __restrict__ eb1, const float* __restrict__ nb2,
    const float* __restrict__ lng, const float* __restrict__ lnb,
    const short* __restrict__ wpk, const float* __restrict__ bfold,
    short* __restrict__ gvb)
{
  __shared__ short lds[8][4160];   // per wave: h 2048 | buf 2048 | mm 64
  const int wave = threadIdx.x >> 6, lane = threadIdx.x & 63;
  const int l15 = lane & 15, lg = lane >> 4;
  const int b = blockIdx.x * 8 + wave;
  short* hs  = &lds[wave][0];
  short* buf = &lds[wave][2048];
  short* mms = &lds[wave][4096];
  const int n = nn[b];
  const float cinv = 1.0f / (float)(n < 1 ? 1 : n);
  const bool keep0 = l15 < n, keep1 = (16 + l15) < n;
  const int fb = lg*4;                 // lane's feature base inside an mt tile
  const int sw = (l15 & 7) << 3;       // XOR swizzle (shorts)
  const int rb0 = l15*64, rb1 = (16 + l15)*64;

  float hD[4][2][4];                   // h^T residual stream, fp32 D-layout
  f32x4 acc[4][2];
  float cs[4][4];

  // ---- embed: h0^T = (nf @ embW)^T + b, masked ----
  {
    bf16x8 bfr[2];
#pragma unroll
    for (int nt = 0; nt < 2; ++nt){
      int node = nt*16 + l15;
      bf16x8 a;
#pragma unroll
      for (int e = 0; e < 8; ++e) a[e] = 0;
      if (lg < 2 && node < 20){
        const float* s = nf + (b*20 + node)*16 + lg*8;
        float4 s0 = *(const float4*)(s);
        float4 s1 = *(const float4*)(s + 4);
        union { bf16x8 v; uint32_t u[4]; } q;
        q.u[0] = pk2(s0.x, s0.y); q.u[1] = pk2(s0.z, s0.w);
        q.u[2] = pk2(s1.x, s1.y); q.u[3] = pk2(s1.z, s1.w);
        a = q.v;
      }
      bfr[nt] = a;
    }
    __syncthreads();
#pragma unroll
    for (int mt = 0; mt < 4; ++mt){
      bf16x8 af = *(const bf16x8*)(wpk + (mt*64 + lane)*8);
      f32x4 z = {0.f,0.f,0.f,0.f};
      acc[mt][0] = mfma16(af, bfr[0], z);
      acc[mt][1] = mfma16(af, bfr[1], z);
    }
#pragma unroll
    for (int mt = 0; mt < 4; ++mt){
      float4 bias = *(const float4*)(embb + mt*16 + fb);
#pragma unroll
      for (int nt = 0; nt < 2; ++nt){
        bool kp = nt ? keep1 : keep0;
#pragma unroll
        for (int e = 0; e < 4; ++e){
          float v = acc[mt][nt][e] + ((const float*)&bias)[e];
          hD[mt][nt][e] = kp ? v : 0.f;
        }
        int base = nt ? rb1 : rb0;
        uint32_t w0 = pk2(hD[mt][nt][0], hD[mt][nt][1]);
        uint32_t w1 = pk2(hD[mt][nt][2], hD[mt][nt][3]);
        *(uint2*)&hs[base + ((mt*16 + fb) ^ sw)] = make_uint2(w0, w1);
      }
#pragma unroll
      for (int e = 0; e < 4; ++e){
        float c = hD[mt][0][e] + hD[mt][1][e];
        c += __shfl_xor(c, 1); c += __shfl_xor(c, 2);
        c += __shfl_xor(c, 4); c += __shfl_xor(c, 8);
        cs[mt][e] = c * cinv;
      }
    }
    if (l15 == 0){
#pragma unroll
      for (int mt = 0; mt < 4; ++mt)
        *(uint2*)&mms[mt*16 + fb] = make_uint2(pk2(cs[mt][0], cs[mt][1]),
                                               pk2(cs[mt][2], cs[mt][3]));
    }
  }

  // ---- 3 layers: E1 -> N1' -> N2(+LN) ----
  for (int li = 0; li < 3; ++li){
    const short* wl = wpk + 2048 + li*20480;

    // E1: (edge_in @ We1)^T, K=128 (h | mm)
    __syncthreads();
#pragma unroll
    for (int mt = 0; mt < 4; ++mt){ acc[mt][0] = (f32x4){0.f,0.f,0.f,0.f}; acc[mt][1] = (f32x4){0.f,0.f,0.f,0.f}; }
#pragma unroll
    for (int ks = 0; ks < 4; ++ks){
      bf16x8 bfr0, bfr1;
      if (ks < 2){
        int ko = (ks*32 + lg*8) ^ sw;
        bfr0 = *(const bf16x8*)&hs[rb0 + ko];
        bfr1 = *(const bf16x8*)&hs[rb1 + ko];
      } else {
        bfr0 = *(const bf16x8*)&mms[(ks - 2)*32 + lg*8];
        bfr1 = bfr0;
      }
#pragma unroll
      for (int mt = 0; mt < 4; ++mt){
        bf16x8 af = *(const bf16x8*)(wl + ((ks*4 + mt)*64 + lane)*8);
        acc[mt][0] = mfma16(af, bfr0, acc[mt][0]);
        acc[mt][1] = mfma16(af, bfr1, acc[mt][1]);
      }
    }
#pragma unroll
    for (int mt = 0; mt < 4; ++mt){
      float4 bias = *(const float4*)(eb1 + li*64 + mt*16 + fb);
#pragma unroll
      for (int nt = 0; nt < 2; ++nt){
        float v0 = acc[mt][nt][0] + ((const float*)&bias)[0];
        float v1 = acc[mt][nt][1] + ((const float*)&bias)[1];
        float v2 = acc[mt][nt][2] + ((const float*)&bias)[2];
        float v3 = acc[mt][nt][3] + ((const float*)&bias)[3];
        v0 = v0 > 0.f ? v0 : 0.f; v1 = v1 > 0.f ? v1 : 0.f;
        v2 = v2 > 0.f ? v2 : 0.f; v3 = v3 > 0.f ? v3 : 0.f;
        int base = nt ? rb1 : rb0;
        *(uint2*)&buf[base + ((mt*16 + fb) ^ sw)] = make_uint2(pk2(v0, v1), pk2(v2, v3));
      }
    }

    // N1': (node_in @ [Wn1a|Wfold])^T, K=128 (h | A1)
    __syncthreads();
#pragma unroll
    for (int mt = 0; mt < 4; ++mt){ acc[mt][0] = (f32x4){0.f,0.f,0.f,0.f}; acc[mt][1] = (f32x4){0.f,0.f,0.f,0.f}; }
#pragma unroll
    for (int ks = 0; ks < 4; ++ks){
      const short* src = (ks < 2) ? hs : buf;
      int ko = (((ks & 1)*32) + lg*8) ^ sw;
      bf16x8 bfr0 = *(const bf16x8*)&src[rb0 + ko];
      bf16x8 bfr1 = *(const bf16x8*)&src[rb1 + ko];
#pragma unroll
      for (int mt = 0; mt < 4; ++mt){
        bf16x8 af = *(const bf16x8*)(wl + 8192 + ((ks*4 + mt)*64 + lane)*8);
        acc[mt][0] = mfma16(af, bfr0, acc[mt][0]);
        acc[mt][1] = mfma16(af, bfr1, acc[mt][1]);
      }
    }
#pragma unroll
    for (int mt = 0; mt < 4; ++mt){
      float4 bias = *(const float4*)(bfold + li*64 + mt*16 + fb);
#pragma unroll
      for (int nt = 0; nt < 2; ++nt){
        float v0 = acc[mt][nt][0] + ((const float*)&bias)[0];
        float v1 = acc[mt][nt][1] + ((const float*)&bias)[1];
        float v2 = acc[mt][nt][2] + ((const float*)&bias)[2];
        float v3 = acc[mt][nt][3] + ((const float*)&bias)[3];
        v0 = v0 > 0.f ? v0 : 0.f; v1 = v1 > 0.f ? v1 : 0.f;
        v2 = v2 > 0.f ? v2 : 0.f; v3 = v3 > 0.f ? v3 : 0.f;
        int base = nt ? rb1 : rb0;
        *(uint2*)&buf[base + ((mt*16 + fb) ^ sw)] = make_uint2(pk2(v0, v1), pk2(v2, v3));
      }
    }

    // N2: K=64 from buf; h = mask(LN(h + .))
    __syncthreads();
#pragma unroll
    for (int mt = 0; mt < 4; ++mt){ acc[mt][0] = (f32x4){0.f,0.f,0.f,0.f}; acc[mt][1] = (f32x4){0.f,0.f,0.f,0.f}; }
#pragma unroll
    for (int ks = 0; ks < 2; ++ks){
      int ko = (ks*32 + lg*8) ^ sw;
      bf16x8 bfr0 = *(const bf16x8*)&buf[rb0 + ko];
      bf16x8 bfr1 = *(const bf16x8*)&buf[rb1 + ko];
#pragma unroll
      for (int mt = 0; mt < 4; ++mt){
        bf16x8 af = *(const bf16x8*)(wl + 16384 + ((ks*4 + mt)*64 + lane)*8);
        acc[mt][0] = mfma16(af, bfr0, acc[mt][0]);
        acc[mt][1] = mfma16(af, bfr1, acc[mt][1]);
      }
    }
    float s1a = 0.f, s2a = 0.f, s1b = 0.f, s2b = 0.f;
#pragma unroll
    for (int mt = 0; mt < 4; ++mt){
      float4 bias = *(const float4*)(nb2 + li*64 + mt*16 + fb);
#pragma unroll
      for (int e = 0; e < 4; ++e){
        float va = hD[mt][0][e] + acc[mt][0][e] + ((const float*)&bias)[e];
        float vb = hD[mt][1][e] + acc[mt][1][e] + ((const float*)&bias)[e];
        hD[mt][0][e] = va; hD[mt][1][e] = vb;
        s1a += va; s2a += va*va; s1b += vb; s2b += vb*vb;
      }
    }
    s1a += __shfl_xor(s1a, 16); s1a += __shfl_xor(s1a, 32);
    s2a += __shfl_xor(s2a, 16); s2a += __shfl_xor(s2a, 32);
    s1b += __shfl_xor(s1b, 16); s1b += __shfl_xor(s1b, 32);
    s2b += __shfl_xor(s2b, 16); s2b += __shfl_xor(s2b, 32);
    float meana = s1a * 0.015625f, meanb = s1b * 0.015625f;
    float rstda = rsqrtf(s2a * 0.015625f - meana*meana + 1e-5f);
    float rstdb = rsqrtf(s2b * 0.015625f - meanb*meanb + 1e-5f);
#pragma unroll
    for (int mt = 0; mt < 4; ++mt){
      float4 g = *(const float4*)(lng + li*64 + mt*16 + fb);
      float4 bb = *(const float4*)(lnb + li*64 + mt*16 + fb);
#pragma unroll
      for (int e = 0; e < 4; ++e){
        float ge = ((const float*)&g)[e], be = ((const float*)&bb)[e];
        float ya = (hD[mt][0][e] - meana) * rstda * ge + be;
        float yb = (hD[mt][1][e] - meanb) * rstdb * ge + be;
        ya = keep0 ? ya : 0.f;
        yb = keep1 ? yb : 0.f;
        hD[mt][0][e] = ya; hD[mt][1][e] = yb;
        cs[mt][e] = ya + yb;
      }
      *(uint2*)&hs[rb0 + ((mt*16 + fb) ^ sw)] =
          make_uint2(pk2(hD[mt][0][0], hD[mt][0][1]), pk2(hD[mt][0][2], hD[mt][0][3]));
      *(uint2*)&hs[rb1 + ((mt*16 + fb) ^ sw)] =
          make_uint2(pk2(hD[mt][1][0], hD[mt][1][1]), pk2(hD[mt][1][2], hD[mt][1][3]));
    }
#pragma unroll
    for (int mt = 0; mt < 4; ++mt)
#pragma unroll
      for (int e = 0; e < 4; ++e){
        float c = cs[mt][e];
        c += __shfl_xor(c, 1); c += __shfl_xor(c, 2);
        c += __shfl_xor(c, 4); c += __shfl_xor(c, 8);
        cs[mt][e] = c * cinv;
      }
    if (l15 == 0){
      if (li < 2){
#pragma unroll
        for (int mt = 0; mt < 4; ++mt)
          *(uint2*)&mms[mt*16 + fb] = make_uint2(pk2(cs[mt][0], cs[mt][1]),
                                                 pk2(cs[mt][2], cs[mt][3]));
      } else {
#pragma unroll
        for (int mt = 0; mt < 4; ++mt)
          *(uint2*)(gvb + b*64 + mt*16 + fb) = make_uint2(pk2(cs[mt][0], cs[mt][1]),
                                                          pk2(cs[mt][2], cs[mt][3]));
      }
    }
  }
}

// ---------------- phase B: out = relu(gv@ro_w1+b1) @ w2p + b2p --------------
// 128 rows/block (2 row-tiles per wave): halves w2p re-reads, doubles MFMA
// and store work per weight fetch. Stores are float4, 256B/16-lane group.
__global__ __launch_bounds__(256) void gnn_phaseB(
    const short* __restrict__ gvb, const float* __restrict__ rb1,
    const short* __restrict__ wro1, const short* __restrict__ w2p,
    const float* __restrict__ b2p, float* __restrict__ out)
{
  __shared__ short tl[4][2048];
  const int wave = threadIdx.x >> 6, lane = threadIdx.x & 63;
  const int l15 = lane & 15, lg = lane >> 4;
  const int b0 = blockIdx.x * 128 + wave * 32;

  // t = relu(gv @ ro_w1 + b1) for this wave's 32 rows (2 row-tiles)
  f32x4 tacc[2][4];
#pragma unroll
  for (int rt = 0; rt < 2; ++rt)
#pragma unroll
    for (int nt = 0; nt < 4; ++nt) tacc[rt][nt] = (f32x4){0.f,0.f,0.f,0.f};
#pragma unroll
  for (int ks = 0; ks < 2; ++ks){
    bf16x8 a0 = *(const bf16x8*)&gvb[(size_t)(b0 + l15)*64 + ks*32 + lg*8];
    bf16x8 a1 = *(const bf16x8*)&gvb[(size_t)(b0 + 16 + l15)*64 + ks*32 + lg*8];
#pragma unroll
    for (int nt = 0; nt < 4; ++nt){
      bf16x8 bq = *(const bf16x8*)(wro1 + ((ks*4 + nt)*64 + lane)*8);
      tacc[0][nt] = mfma16(a0, bq, tacc[0][nt]);
      tacc[1][nt] = mfma16(a1, bq, tacc[1][nt]);
    }
  }
  short* tw = tl[wave];
#pragma unroll
  for (int rt = 0; rt < 2; ++rt)
#pragma unroll
    for (int nt = 0; nt < 4; ++nt){
      float bias = rb1[nt*16 + l15];
#pragma unroll
      for (int e = 0; e < 4; ++e){
        int row = rt*16 + lg*4 + e;
        float v = tacc[rt][nt][e] + bias;
        v = v > 0.f ? v : 0.f;
        tw[((row*64) + (nt*16 + l15)) ^ ((row & 7) << 3)] = f2bf(v);
      }
    }
  // A-fragments: rows l15 (rt0) and 16+l15 (rt1); (16+l15)&7 == l15&7
  bf16x8 ta[2][2];
  ta[0][0] = *(const bf16x8*)&tw[((l15*64) + (lg*8))           ^ ((l15 & 7) << 3)];
  ta[0][1] = *(const bf16x8*)&tw[((l15*64) + (32 + lg*8))      ^ ((l15 & 7) << 3)];
  ta[1][0] = *(const bf16x8*)&tw[(((16+l15)*64) + (lg*8))      ^ ((l15 & 7) << 3)];
  ta[1][1] = *(const bf16x8*)&tw[(((16+l15)*64) + (32 + lg*8)) ^ ((l15 & 7) << 3)];

  const int g0 = blockIdx.y * 31;
  const int g1 = (g0 + 31 < 155) ? g0 + 31 : 155;
  for (int g = g0; g < g1; ++g){
    const bf16x8* wp = (const bf16x8*)w2p + g*512;   // [j(4)][ks(2)][lane(64)]
    f32x4 c[2][4];
#pragma unroll
    for (int j = 0; j < 4; ++j){
      bf16x8 w0 = wp[(j*2 + 0)*64 + lane];
      bf16x8 w1 = wp[(j*2 + 1)*64 + lane];
      f32x4 z0 = {0.f,0.f,0.f,0.f}, z1 = {0.f,0.f,0.f,0.f};
      z0 = mfma16(ta[0][0], w0, z0); c[0][j] = mfma16(ta[0][1], w1, z0);
      z1 = mfma16(ta[1][0], w0, z1); c[1][j] = mfma16(ta[1][1], w1, z1);
    }
    int p0 = g*64 + l15*4;
    if (p0 < 9900){
      float4 bias = *(const float4*)(b2p + p0);
#pragma unroll
      for (int rt = 0; rt < 2; ++rt){
        float* o = out + (size_t)(b0 + rt*16 + lg*4)*9900 + p0;
#pragma unroll
        for (int e = 0; e < 4; ++e){
          float4 o4 = make_float4(c[rt][0][e] + bias.x, c[rt][1][e] + bias.y,
                                  c[rt][2][e] + bias.z, c[rt][3][e] + bias.w);
          *(float4*)(o + (size_t)e*9900) = o4;
        }
      }
    }
  }
}

extern "C" void kernel_launch(void* const* d_in, const int* in_sizes, int n_in,
                              void* d_out, int out_size, void* d_ws, size_t ws_size,
                              hipStream_t stream)
{
  const float* nf   = (const float*)d_in[0];
  const int*   nn   = (const int*)d_in[1];
  const float* embw = (const float*)d_in[2];
  const float* embb = (const float*)d_in[3];
  const float* ew1  = (const float*)d_in[4];
  const float* eb1  = (const float*)d_in[5];
  const float* ew2  = (const float*)d_in[6];
  const float* eb2  = (const float*)d_in[7];
  const float* nw1  = (const float*)d_in[8];
  const float* nb1  = (const float*)d_in[9];
  const float* nw2  = (const float*)d_in[10];
  const float* nb2  = (const float*)d_in[11];
  const float* lng  = (const float*)d_in[12];
  const float* lnb  = (const float*)d_in[13];
  const float* rw1  = (const float*)d_in[14];
  const float* rb1  = (const float*)d_in[15];
  const float* rw2  = (const float*)d_in[16];
  const float* rb2  = (const float*)d_in[17];
  float* out = (float*)d_out;

  const int B = in_sizes[0] / 320;   // 16384

  char* ws = (char*)d_ws;
  short* gvb  = (short*)ws;                    // B*64 bf16 = 2,097,152 B
  float* b2p  = (float*)(ws + 2097152);        // 9920 f32   (end 2,136,832)
  float* wfold= (float*)(ws + 2136832);        // 3*4096 f32 (end 2,185,984)
  float* bfold= (float*)(ws + 2185984);        // 3*64 f32   (end 2,186,752)
  short* wpk  = (short*)(ws + 2186752);        // 67584 sh   (end 2,321,920)
  short* w2p  = (short*)(ws + 2321920);        // 634880 sh  (end 3,591,680)

  prep_fold<<<3, 256, 0, stream>>>(ew2, eb2, nw1, nb1, wfold, bfold);
  prep_pack<<<(67584 + 255)/256, 256, 0, stream>>>(embw, ew1, nw1, nw2, rw1, wfold, wpk);
  prep_w2<<<(634880 + 9920 + 255)/256, 256, 0, stream>>>(rw2, rb2, w2p, b2p);
  gnn_phaseA<<<B/8, 512, 0, stream>>>(nf, nn, embb, eb1, nb2, lng, lnb, wpk, bfold, gvb);
  gnn_phaseB<<<dim3(B/128, 5), 256, 0, stream>>>(gvb, rb1, wpk + 63488, w2p, b2p, out);
}

// Round 7
// 455.169 us; speedup vs baseline: 1.1330x; 1.0674x over previous
//
#include <hip/hip_runtime.h>
#include <hip/hip_bf16.h>
#include <stdint.h>

typedef __attribute__((ext_vector_type(8))) short bf16x8;
typedef __attribute__((ext_vector_type(4))) float f32x4;

// explicit round-to-nearest-even f32 -> bf16
__device__ __forceinline__ uint32_t f2bfu(float x){
  union { float f; uint32_t u; } v; v.f = x;
  return (v.u + 0x7FFFu + ((v.u >> 16) & 1u)) >> 16;
}
__device__ __forceinline__ short f2bf(float x){ return (short)(uint16_t)f2bfu(x); }
// pack two f32 -> u32 of 2 bf16, RNE (lo = a, hi = b)
__device__ __forceinline__ uint32_t pk2(float a, float b){
  return (f2bfu(a) & 0xFFFFu) | (f2bfu(b) << 16);
}

__device__ __forceinline__ f32x4 mfma16(bf16x8 a, bf16x8 b, f32x4 c){
  return __builtin_amdgcn_mfma_f32_16x16x32_bf16(a, b, c, 0, 0, 0);
}

// ---------------- prep 1: fold E2 into N1 (parallel, 12 blocks) -------------
// Wfold[l] = We2[l] @ Wn1[l][64:128]  (64x64, fp32)
// bfold[l] = nb1[l] + eb2[l] @ Wn1[l][64:128]
// Accumulation order (m ascending) identical to previous rounds.
__global__ void prep_fold(const float* __restrict__ ew2, const float* __restrict__ eb2,
                          const float* __restrict__ nw1, const float* __restrict__ nb1,
                          float* __restrict__ wfold, float* __restrict__ bfold)
{
  int l = blockIdx.x >> 2, q = blockIdx.x & 3, t = threadIdx.x;
  const float* A  = ew2 + l*4096;            // We2 [64][64]
  const float* Bm = nw1 + l*8192 + 4096;     // Wn1b [64][64]
  for (int i = 0; i < 4; ++i){
    int idx = q*1024 + i*256 + t;
    int r = idx >> 6, c = idx & 63;
    float s = 0.f;
    for (int m = 0; m < 64; ++m) s += A[r*64 + m] * Bm[m*64 + c];
    wfold[l*4096 + idx] = s;
  }
  if (q == 0 && t < 64){
    float s = nb1[l*64 + t];
    const float* e2 = eb2 + l*64;
    for (int m = 0; m < 64; ++m) s += e2[m] * Bm[m*64 + t];
    bfold[l*64 + t] = s;
  }
}

// ---------------- prep 2: all static weight packing in ONE kernel -----------
// [0, 67584):                 wpk  — A-fragments of W^T (embed, E1, N1', N2, ro_w1)
// [67584, 67584+634880):      w2p  — ro_w2 with output-permutation + j-interleave
// [+, +9920):                 b2p  — permuted ro_b2
// wpk (shorts): [0,2048) embed (K=16 pad 32)
//   per layer l at 2048 + l*20480: +0 E1(K=128) +8192 N1'(K=128: Wn1a|Wfold) +16384 N2(K=64)
//   ro_w1 at 63488 (K=64). total 67584 shorts.
// frag(ks,mt,lane,e) = W[ks*32 + (lane>>4)*8 + e][mt*16 + (lane&15)]
// w2p layout: [g(155)][j(4)][ks(2)][lane(64)][e(8)]; p = g*64 + (lane&15)*4 + j
__global__ void prep_static(const float* __restrict__ embw,
                            const float* __restrict__ ew1,
                            const float* __restrict__ nw1,
                            const float* __restrict__ nw2,
                            const float* __restrict__ row1,
                            const float* __restrict__ wfold,
                            const float* __restrict__ ro_w2,
                            const float* __restrict__ ro_b2,
                            short* __restrict__ wpk,
                            short* __restrict__ w2p,
                            float* __restrict__ b2p)
{
  int tid = blockIdx.x*256 + threadIdx.x;
  if (tid < 67584){
    int rem; const float* Wa; const float* Wb = nullptr; int Kact;
    if (tid < 2048){ rem = tid; Wa = embw; Kact = 16; }
    else if (tid < 63488){
      int t2 = tid - 2048, li = t2/20480, r = t2%20480;
      if (r < 8192)       { rem = r;         Wa = ew1 + li*8192; Wb = Wa + 4096;        Kact = 128; }
      else if (r < 16384) { rem = r - 8192;  Wa = nw1 + li*8192; Wb = wfold + li*4096;  Kact = 128; }
      else                { rem = r - 16384; Wa = nw2 + li*4096;                         Kact = 64; }
    } else { rem = tid - 63488; Wa = row1; Kact = 64; }
    int e = rem & 7, lane = (rem >> 3) & 63, mt = (rem >> 9) & 3, ks = rem >> 11;
    int k = ks*32 + (lane >> 4)*8 + e;
    int col = mt*16 + (lane & 15);
    float v = 0.f;
    if (k < Kact) v = (k < 64) ? Wa[k*64 + col] : Wb[(k - 64)*64 + col];
    wpk[tid] = f2bf(v);
  } else if (tid < 67584 + 634880){
    int t = tid - 67584;
    int e = t & 7, lane = (t >> 3) & 63, ks = (t >> 9) & 1, j = (t >> 10) & 3, g = t >> 12;
    int k = ks*32 + (lane >> 4)*8 + e;
    int p = g*64 + (lane & 15)*4 + j;
    float v = 0.f;
    if (p < 9900){ int c = p / 900, rm = p % 900; v = ro_w2[k*9900 + rm*11 + c]; }
    w2p[t] = f2bf(v);
  } else if (tid < 67584 + 634880 + 9920){
    int p = tid - 67584 - 634880;
    float v = 0.f;
    if (p < 9900){ int c = p / 900, rm = p % 900; v = ro_b2[rm*11 + c]; }
    b2p[p] = v;
  }
}

// ---------------- phase A: transposed chain; one wave == one batch ----------
// 8 waves/block; per-stage __syncthreads() clusters the 8 waves' identical
// weight-fragment loads in time so L1 serves 7 of 8.
__global__ __launch_bounds__(512) void gnn_phaseA(
    const float* __restrict__ nf, const int* __restrict__ nn,
    const float* __restrict__ embb,
    const float* __restrict__ eb1, const float* __restrict__ nb2,
    const float* __restrict__ lng, const float* __restrict__ lnb,
    const short* __restrict__ wpk, const float* __restrict__ bfold,
    short* __restrict__ gvb)
{
  __shared__ short lds[8][4160];   // per wave: h 2048 | buf 2048 | mm 64
  const int wave = threadIdx.x >> 6, lane = threadIdx.x & 63;
  const int l15 = lane & 15, lg = lane >> 4;
  const int b = blockIdx.x * 8 + wave;
  short* hs  = &lds[wave][0];
  short* buf = &lds[wave][2048];
  short* mms = &lds[wave][4096];
  const int n = nn[b];
  const float cinv = 1.0f / (float)(n < 1 ? 1 : n);
  const bool keep0 = l15 < n, keep1 = (16 + l15) < n;
  const int fb = lg*4;                 // lane's feature base inside an mt tile
  const int sw = (l15 & 7) << 3;       // XOR swizzle (shorts)
  const int rb0 = l15*64, rb1 = (16 + l15)*64;

  float hD[4][2][4];                   // h^T residual stream, fp32 D-layout
  f32x4 acc[4][2];
  float cs[4][4];

  // ---- embed: h0^T = (nf @ embW)^T + b, masked ----
  {
    bf16x8 bfr[2];
#pragma unroll
    for (int nt = 0; nt < 2; ++nt){
      int node = nt*16 + l15;
      bf16x8 a;
#pragma unroll
      for (int e = 0; e < 8; ++e) a[e] = 0;
      if (lg < 2 && node < 20){
        const float* s = nf + (b*20 + node)*16 + lg*8;
        float4 s0 = *(const float4*)(s);
        float4 s1 = *(const float4*)(s + 4);
        union { bf16x8 v; uint32_t u[4]; } q;
        q.u[0] = pk2(s0.x, s0.y); q.u[1] = pk2(s0.z, s0.w);
        q.u[2] = pk2(s1.x, s1.y); q.u[3] = pk2(s1.z, s1.w);
        a = q.v;
      }
      bfr[nt] = a;
    }
    __syncthreads();
#pragma unroll
    for (int mt = 0; mt < 4; ++mt){
      bf16x8 af = *(const bf16x8*)(wpk + (mt*64 + lane)*8);
      f32x4 z = {0.f,0.f,0.f,0.f};
      acc[mt][0] = mfma16(af, bfr[0], z);
      acc[mt][1] = mfma16(af, bfr[1], z);
    }
#pragma unroll
    for (int mt = 0; mt < 4; ++mt){
      float4 bias = *(const float4*)(embb + mt*16 + fb);
#pragma unroll
      for (int nt = 0; nt < 2; ++nt){
        bool kp = nt ? keep1 : keep0;
#pragma unroll
        for (int e = 0; e < 4; ++e){
          float v = acc[mt][nt][e] + ((const float*)&bias)[e];
          hD[mt][nt][e] = kp ? v : 0.f;
        }
        int base = nt ? rb1 : rb0;
        uint32_t w0 = pk2(hD[mt][nt][0], hD[mt][nt][1]);
        uint32_t w1 = pk2(hD[mt][nt][2], hD[mt][nt][3]);
        *(uint2*)&hs[base + ((mt*16 + fb) ^ sw)] = make_uint2(w0, w1);
      }
#pragma unroll
      for (int e = 0; e < 4; ++e){
        float c = hD[mt][0][e] + hD[mt][1][e];
        c += __shfl_xor(c, 1); c += __shfl_xor(c, 2);
        c += __shfl_xor(c, 4); c += __shfl_xor(c, 8);
        cs[mt][e] = c * cinv;
      }
    }
    if (l15 == 0){
#pragma unroll
      for (int mt = 0; mt < 4; ++mt)
        *(uint2*)&mms[mt*16 + fb] = make_uint2(pk2(cs[mt][0], cs[mt][1]),
                                               pk2(cs[mt][2], cs[mt][3]));
    }
  }

  // ---- 3 layers: E1 -> N1' -> N2(+LN) ----
  for (int li = 0; li < 3; ++li){
    const short* wl = wpk + 2048 + li*20480;

    // E1: (edge_in @ We1)^T, K=128 (h | mm)
    __syncthreads();
#pragma unroll
    for (int mt = 0; mt < 4; ++mt){ acc[mt][0] = (f32x4){0.f,0.f,0.f,0.f}; acc[mt][1] = (f32x4){0.f,0.f,0.f,0.f}; }
#pragma unroll
    for (int ks = 0; ks < 4; ++ks){
      bf16x8 bfr0, bfr1;
      if (ks < 2){
        int ko = (ks*32 + lg*8) ^ sw;
        bfr0 = *(const bf16x8*)&hs[rb0 + ko];
        bfr1 = *(const bf16x8*)&hs[rb1 + ko];
      } else {
        bfr0 = *(const bf16x8*)&mms[(ks - 2)*32 + lg*8];
        bfr1 = bfr0;
      }
#pragma unroll
      for (int mt = 0; mt < 4; ++mt){
        bf16x8 af = *(const bf16x8*)(wl + ((ks*4 + mt)*64 + lane)*8);
        acc[mt][0] = mfma16(af, bfr0, acc[mt][0]);
        acc[mt][1] = mfma16(af, bfr1, acc[mt][1]);
      }
    }
#pragma unroll
    for (int mt = 0; mt < 4; ++mt){
      float4 bias = *(const float4*)(eb1 + li*64 + mt*16 + fb);
#pragma unroll
      for (int nt = 0; nt < 2; ++nt){
        float v0 = acc[mt][nt][0] + ((const float*)&bias)[0];
        float v1 = acc[mt][nt][1] + ((const float*)&bias)[1];
        float v2 = acc[mt][nt][2] + ((const float*)&bias)[2];
        float v3 = acc[mt][nt][3] + ((const float*)&bias)[3];
        v0 = v0 > 0.f ? v0 : 0.f; v1 = v1 > 0.f ? v1 : 0.f;
        v2 = v2 > 0.f ? v2 : 0.f; v3 = v3 > 0.f ? v3 : 0.f;
        int base = nt ? rb1 : rb0;
        *(uint2*)&buf[base + ((mt*16 + fb) ^ sw)] = make_uint2(pk2(v0, v1), pk2(v2, v3));
      }
    }

    // N1': (node_in @ [Wn1a|Wfold])^T, K=128 (h | A1)
    __syncthreads();
#pragma unroll
    for (int mt = 0; mt < 4; ++mt){ acc[mt][0] = (f32x4){0.f,0.f,0.f,0.f}; acc[mt][1] = (f32x4){0.f,0.f,0.f,0.f}; }
#pragma unroll
    for (int ks = 0; ks < 4; ++ks){
      const short* src = (ks < 2) ? hs : buf;
      int ko = (((ks & 1)*32) + lg*8) ^ sw;
      bf16x8 bfr0 = *(const bf16x8*)&src[rb0 + ko];
      bf16x8 bfr1 = *(const bf16x8*)&src[rb1 + ko];
#pragma unroll
      for (int mt = 0; mt < 4; ++mt){
        bf16x8 af = *(const bf16x8*)(wl + 8192 + ((ks*4 + mt)*64 + lane)*8);
        acc[mt][0] = mfma16(af, bfr0, acc[mt][0]);
        acc[mt][1] = mfma16(af, bfr1, acc[mt][1]);
      }
    }
#pragma unroll
    for (int mt = 0; mt < 4; ++mt){
      float4 bias = *(const float4*)(bfold + li*64 + mt*16 + fb);
#pragma unroll
      for (int nt = 0; nt < 2; ++nt){
        float v0 = acc[mt][nt][0] + ((const float*)&bias)[0];
        float v1 = acc[mt][nt][1] + ((const float*)&bias)[1];
        float v2 = acc[mt][nt][2] + ((const float*)&bias)[2];
        float v3 = acc[mt][nt][3] + ((const float*)&bias)[3];
        v0 = v0 > 0.f ? v0 : 0.f; v1 = v1 > 0.f ? v1 : 0.f;
        v2 = v2 > 0.f ? v2 : 0.f; v3 = v3 > 0.f ? v3 : 0.f;
        int base = nt ? rb1 : rb0;
        *(uint2*)&buf[base + ((mt*16 + fb) ^ sw)] = make_uint2(pk2(v0, v1), pk2(v2, v3));
      }
    }

    // N2: K=64 from buf; h = mask(LN(h + .))
    __syncthreads();
#pragma unroll
    for (int mt = 0; mt < 4; ++mt){ acc[mt][0] = (f32x4){0.f,0.f,0.f,0.f}; acc[mt][1] = (f32x4){0.f,0.f,0.f,0.f}; }
#pragma unroll
    for (int ks = 0; ks < 2; ++ks){
      int ko = (ks*32 + lg*8) ^ sw;
      bf16x8 bfr0 = *(const bf16x8*)&buf[rb0 + ko];
      bf16x8 bfr1 = *(const bf16x8*)&buf[rb1 + ko];
#pragma unroll
      for (int mt = 0; mt < 4; ++mt){
        bf16x8 af = *(const bf16x8*)(wl + 16384 + ((ks*4 + mt)*64 + lane)*8);
        acc[mt][0] = mfma16(af, bfr0, acc[mt][0]);
        acc[mt][1] = mfma16(af, bfr1, acc[mt][1]);
      }
    }
    float s1a = 0.f, s2a = 0.f, s1b = 0.f, s2b = 0.f;
#pragma unroll
    for (int mt = 0; mt < 4; ++mt){
      float4 bias = *(const float4*)(nb2 + li*64 + mt*16 + fb);
#pragma unroll
      for (int e = 0; e < 4; ++e){
        float va = hD[mt][0][e] + acc[mt][0][e] + ((const float*)&bias)[e];
        float vb = hD[mt][1][e] + acc[mt][1][e] + ((const float*)&bias)[e];
        hD[mt][0][e] = va; hD[mt][1][e] = vb;
        s1a += va; s2a += va*va; s1b += vb; s2b += vb*vb;
      }
    }
    s1a += __shfl_xor(s1a, 16); s1a += __shfl_xor(s1a, 32);
    s2a += __shfl_xor(s2a, 16); s2a += __shfl_xor(s2a, 32);
    s1b += __shfl_xor(s1b, 16); s1b += __shfl_xor(s1b, 32);
    s2b += __shfl_xor(s2b, 16); s2b += __shfl_xor(s2b, 32);
    float meana = s1a * 0.015625f, meanb = s1b * 0.015625f;
    float rstda = rsqrtf(s2a * 0.015625f - meana*meana + 1e-5f);
    float rstdb = rsqrtf(s2b * 0.015625f - meanb*meanb + 1e-5f);
#pragma unroll
    for (int mt = 0; mt < 4; ++mt){
      float4 g = *(const float4*)(lng + li*64 + mt*16 + fb);
      float4 bb = *(const float4*)(lnb + li*64 + mt*16 + fb);
#pragma unroll
      for (int e = 0; e < 4; ++e){
        float ge = ((const float*)&g)[e], be = ((const float*)&bb)[e];
        float ya = (hD[mt][0][e] - meana) * rstda * ge + be;
        float yb = (hD[mt][1][e] - meanb) * rstdb * ge + be;
        ya = keep0 ? ya : 0.f;
        yb = keep1 ? yb : 0.f;
        hD[mt][0][e] = ya; hD[mt][1][e] = yb;
        cs[mt][e] = ya + yb;
      }
      *(uint2*)&hs[rb0 + ((mt*16 + fb) ^ sw)] =
          make_uint2(pk2(hD[mt][0][0], hD[mt][0][1]), pk2(hD[mt][0][2], hD[mt][0][3]));
      *(uint2*)&hs[rb1 + ((mt*16 + fb) ^ sw)] =
          make_uint2(pk2(hD[mt][1][0], hD[mt][1][1]), pk2(hD[mt][1][2], hD[mt][1][3]));
    }
#pragma unroll
    for (int mt = 0; mt < 4; ++mt)
#pragma unroll
      for (int e = 0; e < 4; ++e){
        float c = cs[mt][e];
        c += __shfl_xor(c, 1); c += __shfl_xor(c, 2);
        c += __shfl_xor(c, 4); c += __shfl_xor(c, 8);
        cs[mt][e] = c * cinv;
      }
    if (l15 == 0){
      if (li < 2){
#pragma unroll
        for (int mt = 0; mt < 4; ++mt)
          *(uint2*)&mms[mt*16 + fb] = make_uint2(pk2(cs[mt][0], cs[mt][1]),
                                                 pk2(cs[mt][2], cs[mt][3]));
      } else {
#pragma unroll
        for (int mt = 0; mt < 4; ++mt)
          *(uint2*)(gvb + b*64 + mt*16 + fb) = make_uint2(pk2(cs[mt][0], cs[mt][1]),
                                                          pk2(cs[mt][2], cs[mt][3]));
      }
    }
  }
}

// ---------------- phase B: out = relu(gv@ro_w1+b1) @ w2p + b2p --------------
// 128 rows/block (2 row-tiles per wave); float4 stores, 256B/16-lane group.
__global__ __launch_bounds__(256) void gnn_phaseB(
    const short* __restrict__ gvb, const float* __restrict__ rb1,
    const short* __restrict__ wro1, const short* __restrict__ w2p,
    const float* __restrict__ b2p, float* __restrict__ out)
{
  __shared__ short tl[4][2048];
  const int wave = threadIdx.x >> 6, lane = threadIdx.x & 63;
  const int l15 = lane & 15, lg = lane >> 4;
  const int b0 = blockIdx.x * 128 + wave * 32;

  // t = relu(gv @ ro_w1 + b1) for this wave's 32 rows (2 row-tiles)
  f32x4 tacc[2][4];
#pragma unroll
  for (int rt = 0; rt < 2; ++rt)
#pragma unroll
    for (int nt = 0; nt < 4; ++nt) tacc[rt][nt] = (f32x4){0.f,0.f,0.f,0.f};
#pragma unroll
  for (int ks = 0; ks < 2; ++ks){
    bf16x8 a0 = *(const bf16x8*)&gvb[(size_t)(b0 + l15)*64 + ks*32 + lg*8];
    bf16x8 a1 = *(const bf16x8*)&gvb[(size_t)(b0 + 16 + l15)*64 + ks*32 + lg*8];
#pragma unroll
    for (int nt = 0; nt < 4; ++nt){
      bf16x8 bq = *(const bf16x8*)(wro1 + ((ks*4 + nt)*64 + lane)*8);
      tacc[0][nt] = mfma16(a0, bq, tacc[0][nt]);
      tacc[1][nt] = mfma16(a1, bq, tacc[1][nt]);
    }
  }
  short* tw = tl[wave];
#pragma unroll
  for (int rt = 0; rt < 2; ++rt)
#pragma unroll
    for (int nt = 0; nt < 4; ++nt){
      float bias = rb1[nt*16 + l15];
#pragma unroll
      for (int e = 0; e < 4; ++e){
        int row = rt*16 + lg*4 + e;
        float v = tacc[rt][nt][e] + bias;
        v = v > 0.f ? v : 0.f;
        tw[((row*64) + (nt*16 + l15)) ^ ((row & 7) << 3)] = f2bf(v);
      }
    }
  // A-fragments: rows l15 (rt0) and 16+l15 (rt1); (16+l15)&7 == l15&7
  bf16x8 ta[2][2];
  ta[0][0] = *(const bf16x8*)&tw[((l15*64) + (lg*8))           ^ ((l15 & 7) << 3)];
  ta[0][1] = *(const bf16x8*)&tw[((l15*64) + (32 + lg*8))      ^ ((l15 & 7) << 3)];
  ta[1][0] = *(const bf16x8*)&tw[(((16+l15)*64) + (lg*8))      ^ ((l15 & 7) << 3)];
  ta[1][1] = *(const bf16x8*)&tw[(((16+l15)*64) + (32 + lg*8)) ^ ((l15 & 7) << 3)];

  const int g0 = blockIdx.y * 31;
  const int g1 = (g0 + 31 < 155) ? g0 + 31 : 155;
  for (int g = g0; g < g1; ++g){
    const bf16x8* wp = (const bf16x8*)w2p + g*512;   // [j(4)][ks(2)][lane(64)]
    f32x4 c[2][4];
#pragma unroll
    for (int j = 0; j < 4; ++j){
      bf16x8 w0 = wp[(j*2 + 0)*64 + lane];
      bf16x8 w1 = wp[(j*2 + 1)*64 + lane];
      f32x4 z0 = {0.f,0.f,0.f,0.f}, z1 = {0.f,0.f,0.f,0.f};
      z0 = mfma16(ta[0][0], w0, z0); c[0][j] = mfma16(ta[0][1], w1, z0);
      z1 = mfma16(ta[1][0], w0, z1); c[1][j] = mfma16(ta[1][1], w1, z1);
    }
    int p0 = g*64 + l15*4;
    if (p0 < 9900){
      float4 bias = *(const float4*)(b2p + p0);
#pragma unroll
      for (int rt = 0; rt < 2; ++rt){
        float* o = out + (size_t)(b0 + rt*16 + lg*4)*9900 + p0;
#pragma unroll
        for (int e = 0; e < 4; ++e){
          float4 o4 = make_float4(c[rt][0][e] + bias.x, c[rt][1][e] + bias.y,
                                  c[rt][2][e] + bias.z, c[rt][3][e] + bias.w);
          *(float4*)(o + (size_t)e*9900) = o4;
        }
      }
    }
  }
}

extern "C" void kernel_launch(void* const* d_in, const int* in_sizes, int n_in,
                              void* d_out, int out_size, void* d_ws, size_t ws_size,
                              hipStream_t stream)
{
  const float* nf   = (const float*)d_in[0];
  const int*   nn   = (const int*)d_in[1];
  const float* embw = (const float*)d_in[2];
  const float* embb = (const float*)d_in[3];
  const float* ew1  = (const float*)d_in[4];
  const float* eb1  = (const float*)d_in[5];
  const float* ew2  = (const float*)d_in[6];
  const float* eb2  = (const float*)d_in[7];
  const float* nw1  = (const float*)d_in[8];
  const float* nb1  = (const float*)d_in[9];
  const float* nw2  = (const float*)d_in[10];
  const float* nb2  = (const float*)d_in[11];
  const float* lng  = (const float*)d_in[12];
  const float* lnb  = (const float*)d_in[13];
  const float* rw1  = (const float*)d_in[14];
  const float* rb1  = (const float*)d_in[15];
  const float* rw2  = (const float*)d_in[16];
  const float* rb2  = (const float*)d_in[17];
  float* out = (float*)d_out;

  const int B = in_sizes[0] / 320;   // 16384

  char* ws = (char*)d_ws;
  short* gvb  = (short*)ws;                    // B*64 bf16 = 2,097,152 B
  float* b2p  = (float*)(ws + 2097152);        // 9920 f32   (end 2,136,832)
  float* wfold= (float*)(ws + 2136832);        // 3*4096 f32 (end 2,185,984)
  float* bfold= (float*)(ws + 2185984);        // 3*64 f32   (end 2,186,752)
  short* wpk  = (short*)(ws + 2186752);        // 67584 sh   (end 2,321,920)
  short* w2p  = (short*)(ws + 2321920);        // 634880 sh  (end 3,591,680)

  prep_fold<<<12, 256, 0, stream>>>(ew2, eb2, nw1, nb1, wfold, bfold);
  prep_static<<<(67584 + 634880 + 9920 + 255)/256, 256, 0, stream>>>(
      embw, ew1, nw1, nw2, rw1, wfold, rw2, rb2, wpk, w2p, b2p);
  gnn_phaseA<<<B/8, 512, 0, stream>>>(nf, nn, embb, eb1, nb2, lng, lnb, wpk, bfold, gvb);
  gnn_phaseB<<<dim3(B/128, 5), 256, 0, stream>>>(gvb, rb1, wpk + 63488, w2p, b2p, out);
}